// Round 6
// baseline (108.080 us; speedup 1.0000x reference)
//
#include <hip/hip_runtime.h>

// Problem constants (match reference)
constexpr int BN    = 4194304;  // batch
constexpr int C     = 9;        // classes
constexpr int TPB   = 256;      // threads per block
constexpr int RPT   = 4;        // rows per thread (4 rows x 36B = 9 float4, contiguous)
constexpr int NBLK  = 2048;     // grid
constexpr int NITER = BN / (RPT * TPB * NBLK);   // 2

__global__ __launch_bounds__(TPB) void loss_main(
    const float* __restrict__ pred_probs,   // [B,9]
    const int*   __restrict__ true_class,   // [B]
    const float* __restrict__ pred_points,  // [B]
    const float* __restrict__ true_points,  // [B]
    double*      __restrict__ partials,     // [NBLK*2]
    unsigned*    __restrict__ counter,      // zeroed each launch
    float*       __restrict__ out)          // [3]
{
    const float4* pp4 = reinterpret_cast<const float4*>(pred_probs);
    const int4*   tc4 = reinterpret_cast<const int4*>(true_class);
    const float4* a4  = reinterpret_cast<const float4*>(pred_points);
    const float4* b4  = reinterpret_cast<const float4*>(true_points);

    const int t = threadIdx.x;
    float mse_acc = 0.f;
    float ce_acc  = 0.f;

    #pragma unroll
    for (int it = 0; it < NITER; ++it) {
        // global thread-group index; each owns rows [g*4, g*4+4)
        const int g = (it * NBLK + (int)blockIdx.x) * TPB + t;

        // ---- all loads: full 16B vectors from this thread's contiguous span ----
        float4 v[9];
        #pragma unroll
        for (int k = 0; k < 9; ++k) v[k] = pp4[(size_t)g * 9 + k];
        const int4   tc = tc4[g];
        const float4 pa = a4[g];
        const float4 pb = b4[g];

        // ---- MSE ----
        {
            float d0 = pa.x - pb.x, d1 = pa.y - pb.y;
            float d2 = pa.z - pb.z, d3 = pa.w - pb.w;
            mse_acc += d0 * d0 + d1 * d1 + d2 * d2 + d3 * d3;
        }

        // ---- unpack to scalar regs (all indices compile-time) ----
        float a[36];
        #pragma unroll
        for (int k = 0; k < 9; ++k) {
            a[4 * k]     = v[k].x;
            a[4 * k + 1] = v[k].y;
            a[4 * k + 2] = v[k].z;
            a[4 * k + 3] = v[k].w;
        }

        // ---- 4 rows of CE, fully unrolled, no runtime register indexing ----
        #pragma unroll
        for (int r = 0; r < RPT; ++r) {
            const int base = r * C;
            const int tcr = (r == 0) ? tc.x : (r == 1) ? tc.y : (r == 2) ? tc.z : tc.w;
            float m = a[base];
            int am = 0;
            #pragma unroll
            for (int j = 1; j < C; ++j) {
                float x = a[base + j];
                if (x > m) { m = x; am = j; }
            }
            float se = 0.f;
            #pragma unroll
            for (int j = 0; j < C; ++j) se += __expf(a[base + j] - m);
            // row[tcr] via select chain (avoid runtime-indexed array -> scratch)
            float atc = a[base];
            #pragma unroll
            for (int j = 1; j < C; ++j) atc = (tcr == j) ? a[base + j] : atc;
            const float ce_i = m + __logf(se) - atc;
            int d = am - tcr; if (d < 0) d = -d;
            ce_acc += (float)(d + 1) * ce_i;
        }
    }

    // ---- block reduction: wave shfl in double, then LDS across waves ----
    double mse_d = (double)mse_acc;
    double ce_d  = (double)ce_acc;
    #pragma unroll
    for (int off = 32; off > 0; off >>= 1) {
        mse_d += __shfl_down(mse_d, off, 64);
        ce_d  += __shfl_down(ce_d, off, 64);
    }
    __shared__ double wsum[(TPB / 64) * 2];
    __shared__ unsigned s_ticket;
    const int wid = t >> 6;
    if ((t & 63) == 0) { wsum[wid * 2] = mse_d; wsum[wid * 2 + 1] = ce_d; }
    __syncthreads();
    if (t == 0) {
        double ms = 0.0, cs = 0.0;
        #pragma unroll
        for (int w = 0; w < TPB / 64; ++w) { ms += wsum[w * 2]; cs += wsum[w * 2 + 1]; }
        partials[(size_t)blockIdx.x * 2]     = ms;
        partials[(size_t)blockIdx.x * 2 + 1] = cs;
        __threadfence();                        // release partials to device scope
        s_ticket = atomicAdd(counter, 1u);      // device-scope ticket
    }
    __syncthreads();

    // ---- last block to finish reduces all partials and writes out ----
    if (s_ticket == NBLK - 1) {
        __threadfence();                        // acquire all partials
        double ms = 0.0, cs = 0.0;
        for (int b = t; b < NBLK; b += TPB) {
            ms += partials[(size_t)b * 2];
            cs += partials[(size_t)b * 2 + 1];
        }
        #pragma unroll
        for (int off = 32; off > 0; off >>= 1) {
            ms += __shfl_down(ms, off, 64);
            cs += __shfl_down(cs, off, 64);
        }
        __syncthreads();                        // wsum reuse is safe after this
        if ((t & 63) == 0) { wsum[wid * 2] = ms; wsum[wid * 2 + 1] = cs; }
        __syncthreads();
        if (t == 0) {
            double M = 0.0, Cs = 0.0;
            #pragma unroll
            for (int w = 0; w < TPB / 64; ++w) { M += wsum[w * 2]; Cs += wsum[w * 2 + 1]; }
            const double mse = M / (double)BN;
            const double ce  = Cs / (double)BN;
            out[0] = (float)(mse + ce);   // loss = mse + ALPHA*ce, ALPHA=1
            out[1] = (float)mse;
            out[2] = (float)ce;
        }
    }
}

extern "C" void kernel_launch(void* const* d_in, const int* in_sizes, int n_in,
                              void* d_out, int out_size, void* d_ws, size_t ws_size,
                              hipStream_t stream) {
    const float* pred_probs  = (const float*)d_in[0];
    const int*   true_class  = (const int*)d_in[1];
    const float* pred_points = (const float*)d_in[2];
    const float* true_points = (const float*)d_in[3];
    float*    out      = (float*)d_out;
    double*   partials = (double*)d_ws;                          // 32 KB
    unsigned* counter  = (unsigned*)((char*)d_ws + NBLK * 2 * sizeof(double));

    hipMemsetAsync(counter, 0, sizeof(unsigned), stream);        // capture-safe
    loss_main<<<NBLK, TPB, 0, stream>>>(pred_probs, true_class,
                                        pred_points, true_points,
                                        partials, counter, out);
}

// Round 7
// 99.034 us; speedup vs baseline: 1.0913x; 1.0913x over previous
//
#include <hip/hip_runtime.h>

// Problem constants (match reference)
constexpr int BN    = 4194304;  // batch
constexpr int C     = 9;        // classes
constexpr int TPB   = 256;      // threads per block
constexpr int RPT   = 4;        // rows per thread (4 rows x 36B = 9 float4, contiguous)
constexpr int NBLK  = 2048;     // grid
constexpr int NITER = BN / (RPT * TPB * NBLK);   // 2

__global__ __launch_bounds__(TPB) void loss_main(
    const float* __restrict__ pred_probs,   // [B,9]
    const int*   __restrict__ true_class,   // [B]
    const float* __restrict__ pred_points,  // [B]
    const float* __restrict__ true_points,  // [B]
    float*       __restrict__ out)          // [3], zeroed before launch
{
    const float4* pp4 = reinterpret_cast<const float4*>(pred_probs);
    const int4*   tc4 = reinterpret_cast<const int4*>(true_class);
    const float4* a4  = reinterpret_cast<const float4*>(pred_points);
    const float4* b4  = reinterpret_cast<const float4*>(true_points);

    const int t = threadIdx.x;
    float mse_acc = 0.f;
    float ce_acc  = 0.f;

    #pragma unroll
    for (int it = 0; it < NITER; ++it) {
        // global thread-group index; each owns rows [g*4, g*4+4)
        const int g = (it * NBLK + (int)blockIdx.x) * TPB + t;

        // ---- all loads: full 16B vectors from this thread's contiguous span ----
        float4 v[9];
        #pragma unroll
        for (int k = 0; k < 9; ++k) v[k] = pp4[(size_t)g * 9 + k];
        const int4   tc = tc4[g];
        const float4 pa = a4[g];
        const float4 pb = b4[g];

        // ---- MSE ----
        {
            float d0 = pa.x - pb.x, d1 = pa.y - pb.y;
            float d2 = pa.z - pb.z, d3 = pa.w - pb.w;
            mse_acc += d0 * d0 + d1 * d1 + d2 * d2 + d3 * d3;
        }

        // ---- unpack to scalar regs (all indices compile-time) ----
        float a[36];
        #pragma unroll
        for (int k = 0; k < 9; ++k) {
            a[4 * k]     = v[k].x;
            a[4 * k + 1] = v[k].y;
            a[4 * k + 2] = v[k].z;
            a[4 * k + 3] = v[k].w;
        }

        // ---- 4 rows of CE, fully unrolled, no runtime register indexing ----
        #pragma unroll
        for (int r = 0; r < RPT; ++r) {
            const int base = r * C;
            const int tcr = (r == 0) ? tc.x : (r == 1) ? tc.y : (r == 2) ? tc.z : tc.w;
            float m = a[base];
            int am = 0;
            #pragma unroll
            for (int j = 1; j < C; ++j) {
                float x = a[base + j];
                if (x > m) { m = x; am = j; }
            }
            float se = 0.f;
            #pragma unroll
            for (int j = 0; j < C; ++j) se += __expf(a[base + j] - m);
            // row[tcr] via select chain (avoid runtime-indexed array -> scratch)
            float atc = a[base];
            #pragma unroll
            for (int j = 1; j < C; ++j) atc = (tcr == j) ? a[base + j] : atc;
            const float ce_i = m + __logf(se) - atc;
            int d = am - tcr; if (d < 0) d = -d;
            ce_acc += (float)(d + 1) * ce_i;
        }
    }

    // ---- block reduction: wave shfl in double, then LDS across waves ----
    double mse_d = (double)mse_acc;
    double ce_d  = (double)ce_acc;
    #pragma unroll
    for (int off = 32; off > 0; off >>= 1) {
        mse_d += __shfl_down(mse_d, off, 64);
        ce_d  += __shfl_down(ce_d, off, 64);
    }
    __shared__ double wsum[(TPB / 64) * 2];
    const int wid = t >> 6;
    if ((t & 63) == 0) { wsum[wid * 2] = mse_d; wsum[wid * 2 + 1] = ce_d; }
    __syncthreads();
    if (t == 0) {
        double ms = 0.0, cs = 0.0;
        #pragma unroll
        for (int w = 0; w < TPB / 64; ++w) { ms += wsum[w * 2]; cs += wsum[w * 2 + 1]; }
        // ---- direct contribution to outputs: no fence, no second kernel ----
        // device-scope float atomics, resolved at the coherent point; host reads
        // out only after stream sync. Order jitter ~1e-4 << 0.259 threshold.
        atomicAdd(&out[1], (float)(ms / (double)BN));                 // mse
        atomicAdd(&out[2], (float)(cs / (double)BN));                 // ce
        atomicAdd(&out[0], (float)((ms + cs) / (double)BN));          // loss
    }
}

extern "C" void kernel_launch(void* const* d_in, const int* in_sizes, int n_in,
                              void* d_out, int out_size, void* d_ws, size_t ws_size,
                              hipStream_t stream) {
    const float* pred_probs  = (const float*)d_in[0];
    const int*   true_class  = (const int*)d_in[1];
    const float* pred_points = (const float*)d_in[2];
    const float* true_points = (const float*)d_in[3];
    float* out = (float*)d_out;

    hipMemsetAsync(out, 0, 3 * sizeof(float), stream);   // capture-safe tiny fill
    loss_main<<<NBLK, TPB, 0, stream>>>(pred_probs, true_class,
                                        pred_points, true_points, out);
}

// Round 8
// 37.980 us; speedup vs baseline: 2.8457x; 2.6075x over previous
//
#include <hip/hip_runtime.h>

// Problem constants (match reference)
constexpr int BN     = 4194304;  // batch
constexpr int C      = 9;        // classes
constexpr int TPB    = 256;      // threads per block
constexpr int TILE   = 1024;     // rows staged per block-iteration
constexpr int NTILES = BN / TILE;        // 4096
constexpr int NBLK   = 1024;             // grid size (4 blocks/CU x 256 CUs)

__global__ __launch_bounds__(TPB) void loss_main(
    const float* __restrict__ pred_probs,   // [B,9]
    const int*   __restrict__ true_class,   // [B]
    const float* __restrict__ pred_points,  // [B]
    const float* __restrict__ true_points,  // [B]
    double*      __restrict__ partials)     // [NBLK*2]
{
    __shared__ float lds[TILE * C];              // 36864 B
    float4* lds4 = reinterpret_cast<float4*>(lds);
    const float4* pp4 = reinterpret_cast<const float4*>(pred_probs);
    const float4* a4  = reinterpret_cast<const float4*>(pred_points);
    const float4* b4  = reinterpret_cast<const float4*>(true_points);

    const int t = threadIdx.x;
    float mse_acc = 0.f;
    float ce_acc  = 0.f;

    for (int tile = blockIdx.x; tile < NTILES; tile += gridDim.x) {
        // ---- stage 1024 rows x 9 floats = 2304 float4, coalesced ----
        const float4* src = pp4 + (size_t)tile * (TILE * C / 4);
        #pragma unroll
        for (int k = 0; k < 9; ++k) {
            lds4[t + k * TPB] = src[t + k * TPB];
        }
        // ---- MSE part: 1024 points per tile = 256 float4 each array ----
        {
            float4 a = a4[(size_t)tile * (TILE / 4) + t];
            float4 b = b4[(size_t)tile * (TILE / 4) + t];
            float d0 = a.x - b.x, d1 = a.y - b.y, d2 = a.z - b.z, d3 = a.w - b.w;
            mse_acc += d0 * d0 + d1 * d1 + d2 * d2 + d3 * d3;
        }
        __syncthreads();
        // ---- per-row CE: 4 rows per thread from LDS ----
        #pragma unroll
        for (int r = 0; r < TILE / TPB; ++r) {
            const int lrow = t + r * TPB;
            const int grow = tile * TILE + lrow;
            const float* row = lds + lrow * C;
            float m = row[0];
            int am = 0;
            #pragma unroll
            for (int j = 1; j < C; ++j) {
                float v = row[j];
                if (v > m) { m = v; am = j; }
            }
            float se = 0.f;
            #pragma unroll
            for (int j = 0; j < C; ++j) se += __expf(row[j] - m);
            const int tc = true_class[grow];
            const float ce_i = m + __logf(se) - row[tc];
            int d = am - tc; if (d < 0) d = -d;
            ce_acc += (float)(d + 1) * ce_i;
        }
        __syncthreads();
    }

    // ---- block reduction: wave shfl in double, then LDS across waves ----
    double mse_d = (double)mse_acc;
    double ce_d  = (double)ce_acc;
    #pragma unroll
    for (int off = 32; off > 0; off >>= 1) {
        mse_d += __shfl_down(mse_d, off, 64);
        ce_d  += __shfl_down(ce_d, off, 64);
    }
    __shared__ double wsum[(TPB / 64) * 2];
    const int wid = t >> 6;
    if ((t & 63) == 0) { wsum[wid * 2] = mse_d; wsum[wid * 2 + 1] = ce_d; }
    __syncthreads();
    if (t == 0) {
        double ms = 0.0, cs = 0.0;
        #pragma unroll
        for (int w = 0; w < TPB / 64; ++w) { ms += wsum[w * 2]; cs += wsum[w * 2 + 1]; }
        partials[(size_t)blockIdx.x * 2]     = ms;
        partials[(size_t)blockIdx.x * 2 + 1] = cs;
    }
}

__global__ __launch_bounds__(256) void loss_finalize(
    const double* __restrict__ partials, float* __restrict__ out)
{
    const int t = threadIdx.x;
    double ms = 0.0, cs = 0.0;
    for (int b = t; b < NBLK; b += 256) {
        ms += partials[(size_t)b * 2];
        cs += partials[(size_t)b * 2 + 1];
    }
    #pragma unroll
    for (int off = 32; off > 0; off >>= 1) {
        ms += __shfl_down(ms, off, 64);
        cs += __shfl_down(cs, off, 64);
    }
    __shared__ double w[8];
    const int wid = t >> 6;
    if ((t & 63) == 0) { w[wid * 2] = ms; w[wid * 2 + 1] = cs; }
    __syncthreads();
    if (t == 0) {
        double M = 0.0, Cs = 0.0;
        #pragma unroll
        for (int i = 0; i < 4; ++i) { M += w[i * 2]; Cs += w[i * 2 + 1]; }
        const double mse = M / (double)BN;
        const double ce  = Cs / (double)BN;
        out[0] = (float)(mse + ce);   // loss = mse + ALPHA*ce, ALPHA=1
        out[1] = (float)mse;
        out[2] = (float)ce;
    }
}

extern "C" void kernel_launch(void* const* d_in, const int* in_sizes, int n_in,
                              void* d_out, int out_size, void* d_ws, size_t ws_size,
                              hipStream_t stream) {
    const float* pred_probs  = (const float*)d_in[0];
    const int*   true_class  = (const int*)d_in[1];
    const float* pred_points = (const float*)d_in[2];
    const float* true_points = (const float*)d_in[3];
    float*  out      = (float*)d_out;
    double* partials = (double*)d_ws;   // NBLK*2 doubles = 16 KB

    loss_main<<<NBLK, TPB, 0, stream>>>(pred_probs, true_class,
                                        pred_points, true_points, partials);
    loss_finalize<<<1, 256, 0, stream>>>(partials, out);
}